// Round 3
// baseline (156.755 us; speedup 1.0000x reference)
//
#include <hip/hip_runtime.h>

#define NB 8
#define NN 2048
#define ND 128

typedef float f32x4 __attribute__((ext_vector_type(4)));
typedef __bf16 bf16x8 __attribute__((ext_vector_type(8)));
typedef unsigned short u16x4 __attribute__((ext_vector_type(4)));

__device__ __forceinline__ unsigned short f2bf(float f) {
  unsigned u = __builtin_bit_cast(unsigned, f);
  u = (u + 0x7FFFu + ((u >> 16) & 1u)) >> 16;
  return (unsigned short)u;
}

// K1: h = x @ W^T + b (fp32). Emit hn = L2norm(h) as bf16 [B*N, D] (row-major)
// and hT = h as bf16 [B, D, N] (feature-major, PV B-operand layout).
__global__ __launch_bounds__(512, 2) void k_linear(
    const float* __restrict__ x, const float* __restrict__ W,
    const float* __restrict__ bias,
    unsigned short* __restrict__ hn, unsigned short* __restrict__ hT) {
  __shared__ __align__(16) float xs[128][68];
  __shared__ __align__(16) float wt[128][128];
  const int tid = threadIdx.x;
  const int rbase = blockIdx.x * 64;
  const int b = rbase >> 11;
  const int nb = rbase & (NN - 1);

#pragma unroll
  for (int j = 0; j < 4; ++j) {
    int f = tid + j * 512;
    int row = f >> 5;
    int kc = (f & 31) << 2;
    f32x4 v = *reinterpret_cast<const f32x4*>(&x[(size_t)(rbase + row) * ND + kc]);
#pragma unroll
    for (int i2 = 0; i2 < 4; ++i2) {
      int k = kc + i2;
      xs[k][row ^ (k & 28)] = v[i2];
    }
  }
#pragma unroll
  for (int j = 0; j < 8; ++j) {
    int f = tid + j * 512;
    int o = f >> 5;
    int i0 = (f & 31) << 2;
    f32x4 v = *reinterpret_cast<const f32x4*>(&W[(size_t)o * ND + i0]);
#pragma unroll
    for (int i2 = 0; i2 < 4; ++i2) {
      int k = i0 + i2;
      wt[k][o ^ (k & 28)] = v[i2];
    }
  }
  __syncthreads();

  const int tc = tid & 31;
  const int tr = tid >> 5;

  float acc[4][4];
#pragma unroll
  for (int r = 0; r < 4; ++r)
#pragma unroll
    for (int c = 0; c < 4; ++c) acc[r][c] = 0.f;

#pragma unroll 4
  for (int k = 0; k < 128; ++k) {
    const int sw = k & 28;
    f32x4 xv = *reinterpret_cast<const f32x4*>(&xs[k][(tr * 4) ^ sw]);
    f32x4 wv = *reinterpret_cast<const f32x4*>(&wt[k][(tc * 4) ^ sw]);
#pragma unroll
    for (int r = 0; r < 4; ++r)
#pragma unroll
      for (int c = 0; c < 4; ++c) acc[r][c] += xv[r] * wv[c];
  }

  f32x4 bv = *reinterpret_cast<const f32x4*>(&bias[tc * 4]);
#pragma unroll
  for (int r = 0; r < 4; ++r)
#pragma unroll
    for (int c = 0; c < 4; ++c) acc[r][c] += bv[c];

  float inv[4];
#pragma unroll
  for (int r = 0; r < 4; ++r) {
    float s = acc[r][0] * acc[r][0] + acc[r][1] * acc[r][1] +
              acc[r][2] * acc[r][2] + acc[r][3] * acc[r][3];
#pragma unroll
    for (int d = 1; d < 32; d <<= 1) s += __shfl_xor(s, d, 32);
    inv[r] = 1.f / fmaxf(sqrtf(s), 1e-12f);
  }

#pragma unroll
  for (int r = 0; r < 4; ++r) {
    u16x4 hv;
#pragma unroll
    for (int c = 0; c < 4; ++c) hv[c] = f2bf(acc[r][c] * inv[r]);
    *reinterpret_cast<u16x4*>(&hn[(size_t)(rbase + tr * 4 + r) * ND + tc * 4]) = hv;
  }
#pragma unroll
  for (int c = 0; c < 4; ++c) {
    u16x4 tv;
#pragma unroll
    for (int r = 0; r < 4; ++r) tv[r] = f2bf(acc[r][c]);
    *reinterpret_cast<u16x4*>(
        &hT[((size_t)b * ND + tc * 4 + c) * NN + nb + tr * 4]) = tv;
  }
}

// K2: fused out = relu((edge * (hn hn^T)) @ h).
// XCD-batch swizzle: b = bid&7 so (round-robin dispatch) XCD x runs only
// batch x -> hn[b]+hT[b] (1 MB) stays L2-resident per XCD. Edge loads are
// non-temporal so the 16 MB/XCD edge stream doesn't evict it.
__global__ __launch_bounds__(512, 4) void k_fused(
    const float* __restrict__ edge,
    const unsigned short* __restrict__ hn,
    const unsigned short* __restrict__ hT,
    float* __restrict__ out) {
  __shared__ __align__(16) unsigned short p_lds[8][16][68];  // per-wave P tile
  __shared__ __align__(16) float red[2][2][16][132];         // wk-reduce ping-pong
  const int tid = threadIdx.x;
  const int w = tid >> 6;
  const int l = tid & 63;
  const int m = l & 15;
  const int g = l >> 4;
  const int wq = w & 1;   // q sub-tile (16 rows)
  const int wk = w >> 1;  // key quarter (512 keys)

  const int bid = blockIdx.x;
  const int b = bid & 7;    // XCD-batch swizzle
  const int qt = bid >> 3;
  const int q0 = qt * 32 + wq * 16;

  const unsigned short* hnb = hn + (size_t)b * NN * ND;

  // Q as B-fragment: col = m -> q-row q0+m, k = g*8 (+32*kst)
  bf16x8 bq[4];
  {
    const unsigned short* qp = hnb + (size_t)(q0 + m) * ND + g * 8;
#pragma unroll
    for (int kst = 0; kst < 4; ++kst)
      bq[kst] = *reinterpret_cast<const bf16x8*>(qp + kst * 32);
  }

  f32x4 acc_o[8];
#pragma unroll
  for (int i = 0; i < 8; ++i) acc_o[i] = (f32x4){0.f, 0.f, 0.f, 0.f};

  // edge row for this lane's q (= q0+m), within this wave's key quarter
  const float* ep = edge + (size_t)b * NN * NN + (size_t)(q0 + m) * NN + wk * 512;
  const unsigned short* vbase = hT + ((size_t)b * ND + m) * NN;

  f32x4 eg[4];
#pragma unroll
  for (int ct = 0; ct < 4; ++ct)
    eg[ct] = __builtin_nontemporal_load(
        reinterpret_cast<const f32x4*>(ep + ct * 16 + g * 4));

  for (int kt = 0; kt < 8; ++kt) {
    const int kb = wk * 512 + kt * 64;

    // S^T = K Q^T : rows = keys, cols = q. A = K rows, B = Q.
    f32x4 st[4];
#pragma unroll
    for (int ct = 0; ct < 4; ++ct) {
      st[ct] = (f32x4){0.f, 0.f, 0.f, 0.f};
      const unsigned short* kp = hnb + (size_t)(kb + ct * 16 + m) * ND + g * 8;
#pragma unroll
      for (int kst = 0; kst < 4; ++kst) {
        bf16x8 ak = *reinterpret_cast<const bf16x8*>(kp + kst * 32);
        st[ct] = __builtin_amdgcn_mfma_f32_16x16x32_bf16(ak, bq[kst], st[ct], 0, 0, 0);
      }
    }

    // prefetch next edge tile (issued after the K loads so compiler-counted
    // vmcnt waits for K fragments don't drain these)
    f32x4 egn[4];
    if (kt < 7) {
      const float* epn = ep + (kt + 1) * 64;
#pragma unroll
      for (int ct = 0; ct < 4; ++ct)
        egn[ct] = __builtin_nontemporal_load(
            reinterpret_cast<const f32x4*>(epn + ct * 16 + g * 4));
    }

    // gate: P^T[key = kb+ct*16+g*4+r][q = q0+m]; edge f32x4 covers r=0..3.
    // pack as P[q][key] in LDS (row = q-sub = m).
#pragma unroll
    for (int ct = 0; ct < 4; ++ct) {
      u16x4 pv;
#pragma unroll
      for (int r = 0; r < 4; ++r) pv[r] = f2bf(eg[ct][r] * st[ct][r]);
      *reinterpret_cast<u16x4*>(&p_lds[w][m][ct * 16 + g * 4]) = pv;
    }
#pragma unroll
    for (int ct = 0; ct < 4; ++ct) eg[ct] = egn[ct];

    // out += P @ h : A = P from LDS (row = q = m), B = hT (col = feature = m)
#pragma unroll
    for (int kst2 = 0; kst2 < 2; ++kst2) {
      bf16x8 ap = *reinterpret_cast<const bf16x8*>(&p_lds[w][m][kst2 * 32 + g * 8]);
      const unsigned short* vp = vbase + kb + kst2 * 32 + g * 8;
#pragma unroll
      for (int ct2 = 0; ct2 < 8; ++ct2) {
        bf16x8 bv2 = *reinterpret_cast<const bf16x8*>(vp + (size_t)ct2 * 16 * NN);
        acc_o[ct2] = __builtin_amdgcn_mfma_f32_16x16x32_bf16(ap, bv2, acc_o[ct2], 0, 0, 0);
      }
    }
  }

  // reduce the 4 key-quarters: wk1->slot0, wk2->slot1; wk0 adds; wk3->slot0; wk0 adds.
  if (wk == 1 || wk == 2) {
    const int slot = wk - 1;
#pragma unroll
    for (int ct2 = 0; ct2 < 8; ++ct2)
#pragma unroll
      for (int r = 0; r < 4; ++r)
        red[wq][slot][g * 4 + r][ct2 * 16 + m] = acc_o[ct2][r];
  }
  __syncthreads();
  if (wk == 0) {
#pragma unroll
    for (int ct2 = 0; ct2 < 8; ++ct2)
#pragma unroll
      for (int r = 0; r < 4; ++r)
        acc_o[ct2][r] += red[wq][0][g * 4 + r][ct2 * 16 + m] +
                         red[wq][1][g * 4 + r][ct2 * 16 + m];
  }
  __syncthreads();
  if (wk == 3) {
#pragma unroll
    for (int ct2 = 0; ct2 < 8; ++ct2)
#pragma unroll
      for (int r = 0; r < 4; ++r)
        red[wq][0][g * 4 + r][ct2 * 16 + m] = acc_o[ct2][r];
  }
  __syncthreads();
  if (wk == 0) {
    float* ob = out + ((size_t)b * NN + q0) * ND;
#pragma unroll
    for (int ct2 = 0; ct2 < 8; ++ct2)
#pragma unroll
      for (int r = 0; r < 4; ++r) {
        float v = acc_o[ct2][r] + red[wq][0][g * 4 + r][ct2 * 16 + m];
        ob[(g * 4 + r) * ND + ct2 * 16 + m] = fmaxf(v, 0.f);
      }
  }
}

extern "C" void kernel_launch(void* const* d_in, const int* in_sizes, int n_in,
                              void* d_out, int out_size, void* d_ws, size_t ws_size,
                              hipStream_t stream) {
  const float* x = (const float*)d_in[0];
  const float* edge = (const float*)d_in[1];
  const float* W = (const float*)d_in[2];
  const float* bias = (const float*)d_in[3];
  float* out = (float*)d_out;

  unsigned short* hn = (unsigned short*)d_ws;
  unsigned short* hT = hn + (size_t)NB * NN * ND;

  k_linear<<<dim3((NB * NN) / 64), dim3(512), 0, stream>>>(x, W, bias, hn, hT);
  k_fused<<<dim3(NB * (NN / 32)), dim3(512), 0, stream>>>(edge, hn, hT, out);
}

// Round 4
// 89.591 us; speedup vs baseline: 1.7497x; 1.7497x over previous
//
#include <hip/hip_runtime.h>

#define NB 8
#define NN 2048
#define ND 128

typedef float f32x4 __attribute__((ext_vector_type(4)));
typedef __bf16 bf16x8 __attribute__((ext_vector_type(8)));
typedef unsigned short u16x4 __attribute__((ext_vector_type(4)));

__device__ __forceinline__ unsigned short f2bf(float f) {
  unsigned u = __builtin_bit_cast(unsigned, f);
  u = (u + 0x7FFFu + ((u >> 16) & 1u)) >> 16;
  return (unsigned short)u;
}

// async 16B global->LDS (DMA path, bypasses VGPRs and the per-lane miss queue)
__device__ __forceinline__ void stage16(const void* g, void* l) {
  __builtin_amdgcn_global_load_lds(
      (const __attribute__((address_space(1))) unsigned int*)g,
      (__attribute__((address_space(3))) unsigned int*)l, 16, 0, 0);
}

// K1: h = x @ W^T + b (fp32). hn = L2norm(h) bf16 [B*N, D]; hT = h bf16 [B, D, N].
__global__ __launch_bounds__(512, 2) void k_linear(
    const float* __restrict__ x, const float* __restrict__ W,
    const float* __restrict__ bias,
    unsigned short* __restrict__ hn, unsigned short* __restrict__ hT) {
  __shared__ __align__(16) float xs[128][68];
  __shared__ __align__(16) float wt[128][128];
  const int tid = threadIdx.x;
  const int rbase = blockIdx.x * 64;
  const int b = rbase >> 11;
  const int nb = rbase & (NN - 1);

#pragma unroll
  for (int j = 0; j < 4; ++j) {
    int f = tid + j * 512;
    int row = f >> 5;
    int kc = (f & 31) << 2;
    f32x4 v = *reinterpret_cast<const f32x4*>(&x[(size_t)(rbase + row) * ND + kc]);
#pragma unroll
    for (int i2 = 0; i2 < 4; ++i2) {
      int k = kc + i2;
      xs[k][row ^ (k & 28)] = v[i2];
    }
  }
#pragma unroll
  for (int j = 0; j < 8; ++j) {
    int f = tid + j * 512;
    int o = f >> 5;
    int i0 = (f & 31) << 2;
    f32x4 v = *reinterpret_cast<const f32x4*>(&W[(size_t)o * ND + i0]);
#pragma unroll
    for (int i2 = 0; i2 < 4; ++i2) {
      int k = i0 + i2;
      wt[k][o ^ (k & 28)] = v[i2];
    }
  }
  __syncthreads();

  const int tc = tid & 31;
  const int tr = tid >> 5;

  float acc[4][4];
#pragma unroll
  for (int r = 0; r < 4; ++r)
#pragma unroll
    for (int c = 0; c < 4; ++c) acc[r][c] = 0.f;

#pragma unroll 4
  for (int k = 0; k < 128; ++k) {
    const int sw = k & 28;
    f32x4 xv = *reinterpret_cast<const f32x4*>(&xs[k][(tr * 4) ^ sw]);
    f32x4 wv = *reinterpret_cast<const f32x4*>(&wt[k][(tc * 4) ^ sw]);
#pragma unroll
    for (int r = 0; r < 4; ++r)
#pragma unroll
      for (int c = 0; c < 4; ++c) acc[r][c] += xv[r] * wv[c];
  }

  f32x4 bv = *reinterpret_cast<const f32x4*>(&bias[tc * 4]);
#pragma unroll
  for (int r = 0; r < 4; ++r)
#pragma unroll
    for (int c = 0; c < 4; ++c) acc[r][c] += bv[c];

  float inv[4];
#pragma unroll
  for (int r = 0; r < 4; ++r) {
    float s = acc[r][0] * acc[r][0] + acc[r][1] * acc[r][1] +
              acc[r][2] * acc[r][2] + acc[r][3] * acc[r][3];
#pragma unroll
    for (int d = 1; d < 32; d <<= 1) s += __shfl_xor(s, d, 32);
    inv[r] = 1.f / fmaxf(sqrtf(s), 1e-12f);
  }

#pragma unroll
  for (int r = 0; r < 4; ++r) {
    u16x4 hv;
#pragma unroll
    for (int c = 0; c < 4; ++c) hv[c] = f2bf(acc[r][c] * inv[r]);
    *reinterpret_cast<u16x4*>(&hn[(size_t)(rbase + tr * 4 + r) * ND + tc * 4]) = hv;
  }
#pragma unroll
  for (int c = 0; c < 4; ++c) {
    u16x4 tv;
#pragma unroll
    for (int r = 0; r < 4; ++r) tv[r] = f2bf(acc[r][c]);
    *reinterpret_cast<u16x4*>(
        &hT[((size_t)b * ND + tc * 4 + c) * NN + nb + tr * 4]) = tv;
  }
}

// K2: out += (edge * (hn hn^T)) @ h  for this block's 512-key range (fp32 atomics).
// 512 blocks = (b = bid&7 [XCD], qt = 128 q-rows, kh = key quarter), 8 waves.
// K (64x128 bf16) and V (128x64 bf16) tiles staged per block via global_load_lds
// with involutive XOR swizzle: LDS linear dest + inverse-swizzled global source,
// swizzled ds_read (rule #21).
__global__ __launch_bounds__(512, 4) void k_fused(
    const float* __restrict__ edge,
    const unsigned short* __restrict__ hn,
    const unsigned short* __restrict__ hT,
    float* __restrict__ out) {
  __shared__ __align__(16) unsigned short Klds[64 * 128];  // [key][d], 16B-slot swz
  __shared__ __align__(16) unsigned short Vlds[128 * 64];  // [feat][key], swz
  __shared__ __align__(16) unsigned short p_lds[8][16][68];

  const int tid = threadIdx.x;
  const int w = tid >> 6;
  const int l = tid & 63;
  const int m = l & 15;
  const int g = l >> 4;

  const int bid = blockIdx.x;
  const int b = bid & 7;          // XCD-batch affinity
  const int qt = (bid >> 3) & 15;
  const int kh = bid >> 7;        // 0..3 key quarter

  const int q0 = qt * 128 + w * 16;
  const unsigned short* hnb = hn + (size_t)b * NN * ND;
  const unsigned short* hTb = hT + (size_t)b * ND * NN;

  // Q fragments (one-time, 16 q-rows of hn)
  bf16x8 bq[4];
  {
    const unsigned short* qp = hnb + (size_t)(q0 + m) * ND + g * 8;
#pragma unroll
    for (int kst = 0; kst < 4; ++kst)
      bq[kst] = *reinterpret_cast<const bf16x8*>(qp + kst * 32);
  }

  f32x4 acc_o[8];
#pragma unroll
  for (int i = 0; i < 8; ++i) acc_o[i] = (f32x4){0.f, 0.f, 0.f, 0.f};

  const float* ep = edge + (size_t)b * NN * NN + (size_t)(q0 + m) * NN + kh * 512;

  for (int kt = 0; kt < 8; ++kt) {
    const int kb = kh * 512 + kt * 64;

    // --- stage K tile: 1024 chunks of 16B; chunk ch -> row r=ch>>4, slot c=ch&15;
    //     source slot = c ^ (r&7) so a swizzled ds_read sees the natural layout.
#pragma unroll
    for (int i = 0; i < 2; ++i) {
      int ch = tid + i * 512;
      int r = ch >> 4, c = ch & 15;
      int sc = c ^ (r & 7);
      stage16(hnb + (size_t)(kb + r) * ND + sc * 8,
              (void*)((char*)Klds + (size_t)(w * 64 + i * 512) * 16));
    }
    // --- stage V tile: row f=ch>>3 (128B rows), slot c=ch&7; src slot = c^(f&7)
#pragma unroll
    for (int i = 0; i < 2; ++i) {
      int ch = tid + i * 512;
      int f = ch >> 3, c = ch & 7;
      int sc = c ^ (f & 7);
      stage16(hTb + (size_t)f * NN + kb + sc * 8,
              (void*)((char*)Vlds + (size_t)(w * 64 + i * 512) * 16));
    }

    // edge for this tile (read-once stream, non-temporal), overlaps staging
    f32x4 eg[4];
#pragma unroll
    for (int ct = 0; ct < 4; ++ct)
      eg[ct] = __builtin_nontemporal_load(
          reinterpret_cast<const f32x4*>(ep + kt * 64 + ct * 16 + g * 4));

    __syncthreads();  // vmcnt(0) drain: staging + edge complete

    // S^T = K Q^T : A = K rows (from LDS, swizzled read), B = Q regs
    f32x4 st[4];
#pragma unroll
    for (int ct = 0; ct < 4; ++ct) {
      st[ct] = (f32x4){0.f, 0.f, 0.f, 0.f};
      const int r = ct * 16 + m;
#pragma unroll
      for (int kst = 0; kst < 4; ++kst) {
        const int slot = (kst * 4 + g) ^ (r & 7);
        bf16x8 ak = *reinterpret_cast<const bf16x8*>(&Klds[r * 128 + slot * 8]);
        st[ct] = __builtin_amdgcn_mfma_f32_16x16x32_bf16(ak, bq[kst], st[ct], 0, 0, 0);
      }
    }

    // gate, pack P[q][key] into per-wave LDS
#pragma unroll
    for (int ct = 0; ct < 4; ++ct) {
      u16x4 pv;
#pragma unroll
      for (int r = 0; r < 4; ++r) pv[r] = f2bf(eg[ct][r] * st[ct][r]);
      *reinterpret_cast<u16x4*>(&p_lds[w][m][ct * 16 + g * 4]) = pv;
    }

    // out += P @ h : A = P (LDS), B = V tile (LDS, swizzled read)
#pragma unroll
    for (int kst2 = 0; kst2 < 2; ++kst2) {
      bf16x8 ap = *reinterpret_cast<const bf16x8*>(&p_lds[w][m][kst2 * 32 + g * 8]);
#pragma unroll
      for (int ct2 = 0; ct2 < 8; ++ct2) {
        const int c = ct2 * 16 + m;
        const int slot = (kst2 * 4 + g) ^ (c & 7);
        bf16x8 bv2 = *reinterpret_cast<const bf16x8*>(&Vlds[c * 64 + slot * 8]);
        acc_o[ct2] = __builtin_amdgcn_mfma_f32_16x16x32_bf16(ap, bv2, acc_o[ct2], 0, 0, 0);
      }
    }

    __syncthreads();  // compute done before next tile's staging overwrites
  }

  // merge the 4 key-quarters across blocks
  float* ob = out + ((size_t)b * NN + q0) * ND;
#pragma unroll
  for (int ct2 = 0; ct2 < 8; ++ct2)
#pragma unroll
    for (int r = 0; r < 4; ++r)
      atomicAdd(&ob[(size_t)(g * 4 + r) * ND + ct2 * 16 + m], acc_o[ct2][r]);
}

__global__ __launch_bounds__(256) void k_relu(float* __restrict__ out, int n4) {
  int i = blockIdx.x * 256 + threadIdx.x;
  if (i < n4) {
    f32x4 v = reinterpret_cast<f32x4*>(out)[i];
#pragma unroll
    for (int j = 0; j < 4; ++j) v[j] = fmaxf(v[j], 0.f);
    reinterpret_cast<f32x4*>(out)[i] = v;
  }
}

extern "C" void kernel_launch(void* const* d_in, const int* in_sizes, int n_in,
                              void* d_out, int out_size, void* d_ws, size_t ws_size,
                              hipStream_t stream) {
  const float* x = (const float*)d_in[0];
  const float* edge = (const float*)d_in[1];
  const float* W = (const float*)d_in[2];
  const float* bias = (const float*)d_in[3];
  float* out = (float*)d_out;

  unsigned short* hn = (unsigned short*)d_ws;
  unsigned short* hT = hn + (size_t)NB * NN * ND;

  hipMemsetAsync(d_out, 0, (size_t)out_size * sizeof(float), stream);
  k_linear<<<dim3((NB * NN) / 64), dim3(512), 0, stream>>>(x, W, bias, hn, hT);
  k_fused<<<dim3(512), dim3(512), 0, stream>>>(edge, hn, hT, out);
  k_relu<<<dim3((out_size / 4 + 255) / 256), dim3(256), 0, stream>>>(out, out_size / 4);
}

// Round 5
// 72.630 us; speedup vs baseline: 2.1583x; 1.2335x over previous
//
#include <hip/hip_runtime.h>

#define NB 8
#define NN 2048
#define ND 128

typedef float f32x4 __attribute__((ext_vector_type(4)));
typedef __bf16 bf16x8 __attribute__((ext_vector_type(8)));
typedef unsigned short u16x4 __attribute__((ext_vector_type(4)));

__device__ __forceinline__ unsigned short f2bf(float f) {
  unsigned u = __builtin_bit_cast(unsigned, f);
  u = (u + 0x7FFFu + ((u >> 16) & 1u)) >> 16;
  return (unsigned short)u;
}

// async 16B global->LDS; LDS dest is wave-uniform base + lane*16 (HW rule)
__device__ __forceinline__ void stage16(const void* g, void* l) {
  __builtin_amdgcn_global_load_lds(
      (const __attribute__((address_space(1))) unsigned int*)g,
      (__attribute__((address_space(3))) unsigned int*)l, 16, 0, 0);
}

// K1: h = x @ W^T + b (fp32). hn = L2norm(h) bf16 [B*N, D]; hT = h bf16 [B, D, N].
__global__ __launch_bounds__(512, 2) void k_linear(
    const float* __restrict__ x, const float* __restrict__ W,
    const float* __restrict__ bias,
    unsigned short* __restrict__ hn, unsigned short* __restrict__ hT) {
  __shared__ __align__(16) float xs[128][68];
  __shared__ __align__(16) float wt[128][128];
  const int tid = threadIdx.x;
  const int rbase = blockIdx.x * 64;
  const int b = rbase >> 11;
  const int nb = rbase & (NN - 1);

#pragma unroll
  for (int j = 0; j < 4; ++j) {
    int f = tid + j * 512;
    int row = f >> 5;
    int kc = (f & 31) << 2;
    f32x4 v = *reinterpret_cast<const f32x4*>(&x[(size_t)(rbase + row) * ND + kc]);
#pragma unroll
    for (int i2 = 0; i2 < 4; ++i2) {
      int k = kc + i2;
      xs[k][row ^ (k & 28)] = v[i2];
    }
  }
#pragma unroll
  for (int j = 0; j < 8; ++j) {
    int f = tid + j * 512;
    int o = f >> 5;
    int i0 = (f & 31) << 2;
    f32x4 v = *reinterpret_cast<const f32x4*>(&W[(size_t)o * ND + i0]);
#pragma unroll
    for (int i2 = 0; i2 < 4; ++i2) {
      int k = i0 + i2;
      wt[k][o ^ (k & 28)] = v[i2];
    }
  }
  __syncthreads();

  const int tc = tid & 31;
  const int tr = tid >> 5;

  float acc[4][4];
#pragma unroll
  for (int r = 0; r < 4; ++r)
#pragma unroll
    for (int c = 0; c < 4; ++c) acc[r][c] = 0.f;

#pragma unroll 4
  for (int k = 0; k < 128; ++k) {
    const int sw = k & 28;
    f32x4 xv = *reinterpret_cast<const f32x4*>(&xs[k][(tr * 4) ^ sw]);
    f32x4 wv = *reinterpret_cast<const f32x4*>(&wt[k][(tc * 4) ^ sw]);
#pragma unroll
    for (int r = 0; r < 4; ++r)
#pragma unroll
      for (int c = 0; c < 4; ++c) acc[r][c] += xv[r] * wv[c];
  }

  f32x4 bv = *reinterpret_cast<const f32x4*>(&bias[tc * 4]);
#pragma unroll
  for (int r = 0; r < 4; ++r)
#pragma unroll
    for (int c = 0; c < 4; ++c) acc[r][c] += bv[c];

  float inv[4];
#pragma unroll
  for (int r = 0; r < 4; ++r) {
    float s = acc[r][0] * acc[r][0] + acc[r][1] * acc[r][1] +
              acc[r][2] * acc[r][2] + acc[r][3] * acc[r][3];
#pragma unroll
    for (int d = 1; d < 32; d <<= 1) s += __shfl_xor(s, d, 32);
    inv[r] = 1.f / fmaxf(sqrtf(s), 1e-12f);
  }

#pragma unroll
  for (int r = 0; r < 4; ++r) {
    u16x4 hv;
#pragma unroll
    for (int c = 0; c < 4; ++c) hv[c] = f2bf(acc[r][c] * inv[r]);
    *reinterpret_cast<u16x4*>(&hn[(size_t)(rbase + tr * 4 + r) * ND + tc * 4]) = hv;
  }
#pragma unroll
  for (int c = 0; c < 4; ++c) {
    u16x4 tv;
#pragma unroll
    for (int r = 0; r < 4; ++r) tv[r] = f2bf(acc[r][c]);
    *reinterpret_cast<u16x4*>(
        &hT[((size_t)b * ND + tc * 4 + c) * NN + nb + tr * 4]) = tv;
  }
}

// K2: out = relu((edge * (hn hn^T)) @ h), single pass.
// 256 blocks = (b = bid&7 [XCD], qt 0..31): 64 q-rows x all 2048 keys.
// 8 waves = wq(0..3) q-subtile x wk(0..1) key-half. Per iteration: stage
// 128-key K (32KB) + V (32KB) tiles, DOUBLE-BUFFERED -> one barrier/tile.
// Key-half partials reduced in-block via LDS (aliased over K buf), fused ReLU.
__global__ __launch_bounds__(512, 2) void k_fused(
    const float* __restrict__ edge,
    const unsigned short* __restrict__ hn,
    const unsigned short* __restrict__ hT,
    float* __restrict__ out) {
  // [0,64K): K 2x(2 halves x 64 rows x 16 slots)  [64K,128K): V 2x(2 x 128 x 8 slots)
  // [128K, +17408): per-wave P tiles. red (32KB) aliases K after last barrier.
  __shared__ __align__(16) char smem[65536 + 65536 + 17408];
  char* Kb = smem;
  char* Vb = smem + 65536;
  unsigned short(*p_lds)[16][68] =
      reinterpret_cast<unsigned short(*)[16][68]>(smem + 131072);
  float(*red)[16][128] = reinterpret_cast<float(*)[16][128]>(smem);

  const int tid = threadIdx.x;
  const int w = tid >> 6;
  const int l = tid & 63;
  const int m = l & 15;
  const int g = l >> 4;
  const int wq = w & 3;   // q sub-tile (16 rows)
  const int wk = w >> 2;  // key half (1024 keys)

  const int bid = blockIdx.x;
  const int b = bid & 7;        // XCD-batch affinity
  const int qt = bid >> 3;      // 0..31
  const int q0 = qt * 64 + wq * 16;

  const unsigned short* hnb = hn + (size_t)b * NN * ND;
  const unsigned short* hTb = hT + (size_t)b * ND * NN;

  // staging index precompute (per-lane source; wave-uniform LDS dest)
  // K: chunk ch = tid + i*512 (0..2047): half=ch>>10, r=(ch&1023)>>4, c=ch&15
  // V: half=ch>>10, f=(ch&1023)>>3, c=ch&7
  auto stage_tile = [&](int kt, int buf) {
#pragma unroll
    for (int i = 0; i < 4; ++i) {
      int ch = tid + i * 512;
      int half = ch >> 10;
      int rem = ch & 1023;
      int r = rem >> 4, c = rem & 15;
      int sc = c ^ (r & 7);
      stage16(hnb + (size_t)(half * 1024 + kt * 128 + r) * ND + sc * 8,
              Kb + buf * 32768 + (w * 64 + i * 512) * 16);
    }
#pragma unroll
    for (int i = 0; i < 4; ++i) {
      int ch = tid + i * 512;
      int half = ch >> 10;
      int rem = ch & 1023;
      int f = rem >> 3, c = rem & 7;
      int sc = c ^ (f & 7);
      stage16(hTb + (size_t)f * NN + half * 1024 + kt * 128 + sc * 8,
              Vb + buf * 32768 + (w * 64 + i * 512) * 16);
    }
  };
  // NOTE: kt*128 above is wrong if halves overlap; fixed below by using 64-key
  // tiles per half: local key r is 0..63, half offset 1024. (kt ranges 0..15,
  // tile covers keys half*1024 + kt*64 .. +63.)

  // Q fragments (16 q-rows of hn, held in registers)
  bf16x8 bq[4];
  {
    const unsigned short* qp = hnb + (size_t)(q0 + m) * ND + g * 8;
#pragma unroll
    for (int kst = 0; kst < 4; ++kst)
      bq[kst] = *reinterpret_cast<const bf16x8*>(qp + kst * 32);
  }

  f32x4 acc_o[8];
#pragma unroll
  for (int i = 0; i < 8; ++i) acc_o[i] = (f32x4){0.f, 0.f, 0.f, 0.f};

  // edge row for lane's q (= q0+m), within this wave's key half
  const float* ep = edge + (size_t)b * NN * NN + (size_t)(q0 + m) * NN + wk * 1024;

  // ---- prologue: stage tile 0 into buf 0, prefetch edge tile 0
  {
#pragma unroll
    for (int i = 0; i < 4; ++i) {
      int ch = tid + i * 512;
      int half = ch >> 10;
      int rem = ch & 1023;
      int r = rem >> 4, c = rem & 15;
      int sc = c ^ (r & 7);
      stage16(hnb + (size_t)(half * 1024 + r) * ND + sc * 8,
              Kb + (w * 64 + i * 512) * 16);
    }
#pragma unroll
    for (int i = 0; i < 4; ++i) {
      int ch = tid + i * 512;
      int half = ch >> 10;
      int rem = ch & 1023;
      int f = rem >> 3, c = rem & 7;
      int sc = c ^ (f & 7);
      stage16(hTb + (size_t)f * NN + half * 1024 + sc * 8,
              Vb + (w * 64 + i * 512) * 16);
    }
  }
  f32x4 eg[4];
#pragma unroll
  for (int ct = 0; ct < 4; ++ct)
    eg[ct] = __builtin_nontemporal_load(
        reinterpret_cast<const f32x4*>(ep + ct * 16 + g * 4));
  __syncthreads();  // tile 0 staged

  for (int kt = 0; kt < 16; ++kt) {
    const int A = kt & 1;

    // ---- issue stage of tile kt+1 into the other buffer (overlaps compute)
    if (kt < 15) {
#pragma unroll
      for (int i = 0; i < 4; ++i) {
        int ch = tid + i * 512;
        int half = ch >> 10;
        int rem = ch & 1023;
        int r = rem >> 4, c = rem & 15;
        int sc = c ^ (r & 7);
        stage16(hnb + (size_t)(half * 1024 + (kt + 1) * 64 + r) * ND + sc * 8,
                Kb + (A ^ 1) * 32768 + (w * 64 + i * 512) * 16);
      }
#pragma unroll
      for (int i = 0; i < 4; ++i) {
        int ch = tid + i * 512;
        int half = ch >> 10;
        int rem = ch & 1023;
        int f = rem >> 3, c = rem & 7;
        int sc = c ^ (f & 7);
        stage16(hTb + (size_t)f * NN + half * 1024 + (kt + 1) * 64 + sc * 8,
                Vb + (A ^ 1) * 32768 + (w * 64 + i * 512) * 16);
      }
    }
    f32x4 egn[4];
    if (kt < 15) {
      const float* epn = ep + (kt + 1) * 64;
#pragma unroll
      for (int ct = 0; ct < 4; ++ct)
        egn[ct] = __builtin_nontemporal_load(
            reinterpret_cast<const f32x4*>(epn + ct * 16 + g * 4));
    }

    const char* Ka = Kb + A * 32768 + wk * 16384;
    const char* Va = Vb + A * 32768 + wk * 16384;

    // ---- S^T = K Q^T (this wave's 64-key half-tile)
    f32x4 st[4];
#pragma unroll
    for (int ct = 0; ct < 4; ++ct) {
      st[ct] = (f32x4){0.f, 0.f, 0.f, 0.f};
      const int rloc = ct * 16 + m;
#pragma unroll
      for (int kst = 0; kst < 4; ++kst) {
        const int slot = (kst * 4 + g) ^ (rloc & 7);
        bf16x8 ak = *reinterpret_cast<const bf16x8*>(Ka + rloc * 256 + slot * 16);
        st[ct] = __builtin_amdgcn_mfma_f32_16x16x32_bf16(ak, bq[kst], st[ct], 0, 0, 0);
      }
    }

    // ---- gate with edge, pack P[q][key] into per-wave LDS
#pragma unroll
    for (int ct = 0; ct < 4; ++ct) {
      u16x4 pv;
#pragma unroll
      for (int r = 0; r < 4; ++r) pv[r] = f2bf(eg[ct][r] * st[ct][r]);
      *reinterpret_cast<u16x4*>(&p_lds[w][m][ct * 16 + g * 4]) = pv;
    }

    // ---- out += P @ h
#pragma unroll
    for (int kst2 = 0; kst2 < 2; ++kst2) {
      bf16x8 ap = *reinterpret_cast<const bf16x8*>(&p_lds[w][m][kst2 * 32 + g * 8]);
#pragma unroll
      for (int ct2 = 0; ct2 < 8; ++ct2) {
        const int c2 = ct2 * 16 + m;
        const int slot = (kst2 * 4 + g) ^ (c2 & 7);
        bf16x8 bv2 = *reinterpret_cast<const bf16x8*>(Va + c2 * 128 + slot * 16);
        acc_o[ct2] = __builtin_amdgcn_mfma_f32_16x16x32_bf16(ap, bv2, acc_o[ct2], 0, 0, 0);
      }
    }

#pragma unroll
    for (int ct = 0; ct < 4; ++ct) eg[ct] = egn[ct];

    // one barrier per tile: drains tile kt+1 staging (vmcnt0) and fences
    // buffer A reads before it's overwritten in iteration kt+2.
    __syncthreads();
  }

  // ---- in-block reduce of the two key-halves (red aliases K region; safe
  // after the final barrier), fused ReLU, store.
  if (wk == 1) {
#pragma unroll
    for (int ct2 = 0; ct2 < 8; ++ct2)
#pragma unroll
      for (int r = 0; r < 4; ++r)
        red[wq][g * 4 + r][ct2 * 16 + m] = acc_o[ct2][r];
  }
  __syncthreads();
  if (wk == 0) {
    float* ob = out + ((size_t)b * NN + q0) * ND;
#pragma unroll
    for (int ct2 = 0; ct2 < 8; ++ct2)
#pragma unroll
      for (int r = 0; r < 4; ++r) {
        float v = acc_o[ct2][r] + red[wq][g * 4 + r][ct2 * 16 + m];
        ob[(size_t)(g * 4 + r) * ND + ct2 * 16 + m] = fmaxf(v, 0.f);
      }
  }
  (void)stage_tile;  // lambda unused (kept logic inline); silences warning
}

extern "C" void kernel_launch(void* const* d_in, const int* in_sizes, int n_in,
                              void* d_out, int out_size, void* d_ws, size_t ws_size,
                              hipStream_t stream) {
  const float* x = (const float*)d_in[0];
  const float* edge = (const float*)d_in[1];
  const float* W = (const float*)d_in[2];
  const float* bias = (const float*)d_in[3];
  float* out = (float*)d_out;

  unsigned short* hn = (unsigned short*)d_ws;
  unsigned short* hT = hn + (size_t)NB * NN * ND;

  k_linear<<<dim3((NB * NN) / 64), dim3(512), 0, stream>>>(x, W, bias, hn, hT);
  k_fused<<<dim3(NB * (NN / 64)), dim3(512), 0, stream>>>(edge, hn, hT, out);
}